// Round 11
// baseline (151.623 us; speedup 1.0000x reference)
//
#include <hip/hip_runtime.h>
#include <hip/hip_bf16.h>
#include <math.h>

#define Bb 512
#define Tt 256
#define Cc 384
#define Hh 64

#define APAD 72    // A-stage / K stride (shorts)
#define WPAD 72    // W stride (shorts)
#define VTP  264   // V^T stride (shorts)
#define QBP  72    // Q stride (shorts)
#define PST  40    // P tile stride (shorts)

// LDS offsets (shorts). Phase A: AST0/AST1 = x-chunk double buffer,
// WB0/WB1 = W double buffer. Phase B/C aliases: K=AST0, VT=AST1 (16896<=18432),
// Q=WB0.. (18432 spans into WB1), P at P0 (5120; 60416 total <= 64512).
#define AST0 0
#define AST1 (256 * APAD)            // 18432
#define WB0  (2 * 256 * APAD)        // 36864
#define WB1  (WB0 + 192 * WPAD)      // 50688
#define P0   (WB0 + 256 * QBP)       // 55296
#define LDST (WB1 + 192 * WPAD)      // 64512 shorts = 129,024 B

typedef __attribute__((ext_vector_type(8))) short short8;
typedef __attribute__((ext_vector_type(4))) short short4_;
typedef __attribute__((ext_vector_type(4))) float float4_;

static __device__ __forceinline__ unsigned short f2bf(float f) {
  __hip_bfloat16 h = __float2bfloat16(f);
  return *reinterpret_cast<unsigned short*>(&h);
}

// ---------------- kernel 0: pack W into transposed bf16 wt[192][384] ----------------
__global__ __launch_bounds__(256) void wtrans_kernel(
    const float* __restrict__ wq, const float* __restrict__ wk,
    const float* __restrict__ wv, unsigned short* __restrict__ wt) {
  __shared__ float tl[384 * 8];
  const int blk = blockIdx.x;
  const int wsel = blk >> 3, n0 = (blk & 7) * 8;
  const float* w = (wsel == 0) ? wq : (wsel == 1) ? wk : wv;
  const int t = threadIdx.x;
#pragma unroll
  for (int i = 0; i < 3; i++) {
    int id = i * 256 + t;
    int row = id >> 1, sg = id & 1;
    float4_ v = *(const float4_*)(w + row * Hh + n0 + sg * 4);
    *(float4_*)(&tl[row * 8 + sg * 4]) = v;
  }
  __syncthreads();
#pragma unroll
  for (int i = 0; i < 12; i++) {
    int id = i * 256 + t;
    int n = id / 384, k = id % 384;
    wt[(size_t)(wsel * 64 + n0 + n) * Cc + k] = f2bf(tl[k * 8 + n]);
  }
}

// ---------------- fused kernel: 2 batches/block, QKV proj + causal flash attn ----------------
// Phase A: double-buffered x-staging AND W -> ONE lgkm-only barrier per chunk
// (was 2; barrier-convoy was the surviving hypothesis after 5 null rounds).
// Phase B: scatter Q/K/V. Then issue next batch's chunk-0/1 + W loads so phase
// C covers their latency. Phase C: swapped-operand flash attn (R8 verified).
// __launch_bounds__ 2nd arg is CUDA BLOCKS/CU semantics (R4 evidence): (512,1)
// = 256-VGPR budget; LDS (129 KB) limits to 1 block/CU anyway.
__global__ __launch_bounds__(512, 1) void fused_kernel(
    const float* __restrict__ x, const unsigned short* __restrict__ wt,
    float* __restrict__ out) {
  __shared__ unsigned short lds[LDST];
  unsigned short* k_lds  = lds + AST0;
  unsigned short* vt_lds = lds + AST1;
  unsigned short* q_lds  = lds + WB0;

  const int t = threadIdx.x;
  const int wid = t >> 6, lane = t & 63;
  const int fr = lane & 15, fg = lane >> 4;
  const int wr = wid >> 1, wc = wid & 1;   // 4x2 wave grid: 64 rows x 96 cols
  const float SC  = 0.05103103630798288f;  // 384^-0.5
  const float L2E = 1.4426950408889634f;

  float4_ av[2][8];
  short8 wv[3];

  // preload batch-0 chunks 0,1 + W chunk 0
  {
    const float* xb = x + (size_t)(blockIdx.x * 2) * Tt * Cc;
#pragma unroll
    for (int buf = 0; buf < 2; buf++)
#pragma unroll
      for (int i = 0; i < 8; i++) {
        int f = i * 512 + t;
        av[buf][i] = *(const float4_*)(xb + (f >> 4) * Cc + buf * 64 + (f & 15) * 4);
      }
#pragma unroll
    for (int i = 0; i < 3; i++) {
      int id = t + i * 512;
      wv[i] = *(const short8*)(wt + (id >> 3) * Cc + (id & 7) * 8);
    }
  }

#pragma unroll 1
  for (int bi = 0; bi < 2; bi++) {
    const int b = blockIdx.x * 2 + bi;
    const float* xb = x + (size_t)b * Tt * Cc;

    // ============== phase A: QKV = x[b] @ W, 1 barrier per chunk ==============
    float4_ acc[4][6];
#pragma unroll
    for (int i = 0; i < 4; i++)
#pragma unroll
      for (int j = 0; j < 6; j++) acc[i][j] = (float4_)0.f;

#pragma unroll
    for (int ks = 0; ks < 6; ks++) {
      const int cur = ks & 1;
      unsigned short* ast = lds + (cur ? AST1 : AST0);
      unsigned short* wbp = lds + (cur ? WB1 : WB0);
      // stage x chunk ks (vmcnt wait for its loads lands here)
#pragma unroll
      for (int i = 0; i < 8; i++) {
        int f = i * 512 + t;
        short4_ pk;
#pragma unroll
        for (int j = 0; j < 4; j++) pk[j] = (short)f2bf(av[cur][i][j]);
        *(short4_*)(&ast[(f >> 4) * APAD + (f & 15) * 4]) = pk;
      }
      // issue x chunk ks+2 into the buffer just consumed
      if (ks < 4) {
#pragma unroll
        for (int i = 0; i < 8; i++) {
          int f = i * 512 + t;
          av[cur][i] = *(const float4_*)(xb + (f >> 4) * Cc + (ks + 2) * 64 + (f & 15) * 4);
        }
      }
      // store W chunk ks; then issue W chunk ks+1 loads
#pragma unroll
      for (int i = 0; i < 3; i++) {
        int id = t + i * 512;
        *(short8*)(&wbp[(id >> 3) * WPAD + (id & 7) * 8]) = wv[i];
      }
      if (ks < 5) {
#pragma unroll
        for (int i = 0; i < 3; i++) {
          int id = t + i * 512;
          wv[i] = *(const short8*)(wt + (id >> 3) * Cc + (ks + 1) * 64 + (id & 7) * 8);
        }
      }
      // the ONE barrier: lgkm drained (stores visible); vm loads stay in flight.
      // Safety: this barrier also drains prev chunk's MFMA ds_reads (issued
      // pre-barrier in program order), so next iter may overwrite that buffer.
      asm volatile("s_waitcnt lgkmcnt(0)" ::: "memory");
      __builtin_amdgcn_s_barrier();
      __builtin_amdgcn_sched_barrier(0);
#pragma unroll
      for (int kk = 0; kk < 2; kk++) {
        short8 af[4], bf[6];
#pragma unroll
        for (int mi = 0; mi < 4; mi++)
          af[mi] = *(const short8*)(&ast[(wr * 64 + mi * 16 + fr) * APAD + kk * 32 + fg * 8]);
#pragma unroll
        for (int ni = 0; ni < 6; ni++)
          bf[ni] = *(const short8*)(&wbp[(wc * 96 + ni * 16 + fr) * WPAD + kk * 32 + fg * 8]);
#pragma unroll
        for (int mi = 0; mi < 4; mi++)
#pragma unroll
          for (int ni = 0; ni < 6; ni++)
            acc[mi][ni] = __builtin_amdgcn_mfma_f32_16x16x32_bf16(af[mi], bf[ni], acc[mi][ni], 0, 0, 0);
      }
    }
    __syncthreads();   // end A: all LDS reads done before aliased scatter

    // ============== phase B: scatter Q/K/V into attention layouts ==============
    // acc D-layout: row = wr*64 + mi*16 + fg*4 + r, col = wc*96 + ni*16 + fr
#pragma unroll
    for (int mi = 0; mi < 4; mi++) {
      int row0 = wr * 64 + mi * 16 + fg * 4;
#pragma unroll
      for (int ni = 0; ni < 6; ni++) {
        int col = wc * 96 + ni * 16 + fr;
        if (wc == 1 && ni >= 2) {          // V -> V^T [h][seq]
          short4_ pk;
#pragma unroll
          for (int r = 0; r < 4; r++) pk[r] = (short)f2bf(acc[mi][ni][r]);
          *(short4_*)(&vt_lds[(col - 128) * VTP + row0]) = pk;
        } else if (wc == 0 && ni < 4) {    // Q -> [seq][h]
#pragma unroll
          for (int r = 0; r < 4; r++)
            q_lds[(row0 + r) * QBP + col] = f2bf(acc[mi][ni][r]);
        } else {                           // K -> [seq][h]
#pragma unroll
          for (int r = 0; r < 4; r++)
            k_lds[(row0 + r) * APAD + (col - 64)] = f2bf(acc[mi][ni][r]);
        }
      }
    }
    __syncthreads();

    // issue NEXT batch's chunk-0/1 + W-chunk-0 loads; phase C hides the latency
    if (bi == 0) {
      const float* xb2 = x + (size_t)(b + 1) * Tt * Cc;
#pragma unroll
      for (int buf = 0; buf < 2; buf++)
#pragma unroll
        for (int i = 0; i < 8; i++) {
          int f = i * 512 + t;
          av[buf][i] = *(const float4_*)(xb2 + (f >> 4) * Cc + buf * 64 + (f & 15) * 4);
        }
#pragma unroll
      for (int i = 0; i < 3; i++) {
        int id = t + i * 512;
        wv[i] = *(const short8*)(wt + (id >> 3) * Cc + (id & 7) * 8);
      }
    }

    // ============== phase C: causal flash attn, swapped operands ==============
    unsigned short* pw = lds + P0 + wid * 16 * PST;   // wave-private [16 q][32 k]

    auto run_tile = [&](int qt) {
      short8 aq0 = *(const short8*)(&q_lds[(qt * 16 + fr) * QBP + fg * 8]);
      short8 aq1 = *(const short8*)(&q_lds[(qt * 16 + fr) * QBP + 32 + fg * 8]);
      float4_ o[4] = {(float4_)0.f, (float4_)0.f, (float4_)0.f, (float4_)0.f};
      float m = -3.0e38f, l = 0.f;
      const int qg = qt * 16 + fr;
      const int ktmax = qt >> 1;
      short8 kf0 = *(const short8*)(&k_lds[fr * APAD + fg * 8]);
      short8 kf1 = *(const short8*)(&k_lds[(16 + fr) * APAD + fg * 8]);
      short8 kf2 = *(const short8*)(&k_lds[fr * APAD + 32 + fg * 8]);
      short8 kf3 = *(const short8*)(&k_lds[(16 + fr) * APAD + 32 + fg * 8]);
      short8 bv0 = *(const short8*)(&vt_lds[fr * VTP + fg * 8]);
      short8 bv1 = *(const short8*)(&vt_lds[(16 + fr) * VTP + fg * 8]);
      short8 bv2 = *(const short8*)(&vt_lds[(32 + fr) * VTP + fg * 8]);
      short8 bv3 = *(const short8*)(&vt_lds[(48 + fr) * VTP + fg * 8]);
      for (int kt = 0; kt <= ktmax; kt++) {
        float4_ s0 = (float4_)0.f, s1 = (float4_)0.f;
        s0 = __builtin_amdgcn_mfma_f32_16x16x32_bf16(kf0, aq0, s0, 0, 0, 0);
        s1 = __builtin_amdgcn_mfma_f32_16x16x32_bf16(kf1, aq0, s1, 0, 0, 0);
        s0 = __builtin_amdgcn_mfma_f32_16x16x32_bf16(kf2, aq1, s0, 0, 0, 0);
        s1 = __builtin_amdgcn_mfma_f32_16x16x32_bf16(kf3, aq1, s1, 0, 0, 0);
        if (kt < ktmax) {
          int kb = (kt + 1) * 32;
          kf0 = *(const short8*)(&k_lds[(kb + fr) * APAD + fg * 8]);
          kf1 = *(const short8*)(&k_lds[(kb + 16 + fr) * APAD + fg * 8]);
          kf2 = *(const short8*)(&k_lds[(kb + fr) * APAD + 32 + fg * 8]);
          kf3 = *(const short8*)(&k_lds[(kb + 16 + fr) * APAD + 32 + fg * 8]);
        }
        bool edge = (kt == ktmax);
        float vs[8];
#pragma unroll
        for (int r = 0; r < 4; r++) {
          int kg0 = kt * 32 + fg * 4 + r;
          float a0 = s0[r] * SC, a1 = s1[r] * SC;
          if (edge && kg0 > qg)      a0 = -3.0e38f;
          if (edge && kg0 + 16 > qg) a1 = -3.0e38f;
          vs[r] = a0; vs[4 + r] = a1;
        }
        float mx = fmaxf(fmaxf(fmaxf(vs[0], vs[1]), fmaxf(vs[2], vs[3])),
                         fmaxf(fmaxf(vs[4], vs[5]), fmaxf(vs[6], vs[7])));
        mx = fmaxf(mx, __shfl_xor(mx, 16));
        mx = fmaxf(mx, __shfl_xor(mx, 32));
        if (!__all(mx - m <= 8.0f)) {   // defer-rescale (T13, THR=8)
          float mn = fmaxf(m, mx);
          float scal = exp2f((m - mn) * L2E);
          l *= scal;
#pragma unroll
          for (int nt = 0; nt < 4; nt++) o[nt] *= scal;
          m = mn;
        }
        float p[8]; float ps = 0.f;
#pragma unroll
        for (int j = 0; j < 8; j++) { p[j] = exp2f((vs[j] - m) * L2E); ps += p[j]; }
        ps += __shfl_xor(ps, 16);
        ps += __shfl_xor(ps, 32);
        l += ps;

        short4_ pk0, pk1;
#pragma unroll
        for (int r = 0; r < 4; r++) { pk0[r] = (short)f2bf(p[r]); pk1[r] = (short)f2bf(p[4 + r]); }
        *(short4_*)(&pw[fr * PST + fg * 4]) = pk0;
        *(short4_*)(&pw[fr * PST + 16 + fg * 4]) = pk1;
        asm volatile("s_waitcnt lgkmcnt(0)" ::: "memory");
        __builtin_amdgcn_sched_barrier(0);
        short8 pb = *(const short8*)(&pw[fr * PST + fg * 8]);
        o[0] = __builtin_amdgcn_mfma_f32_16x16x32_bf16(bv0, pb, o[0], 0, 0, 0);
        o[1] = __builtin_amdgcn_mfma_f32_16x16x32_bf16(bv1, pb, o[1], 0, 0, 0);
        o[2] = __builtin_amdgcn_mfma_f32_16x16x32_bf16(bv2, pb, o[2], 0, 0, 0);
        o[3] = __builtin_amdgcn_mfma_f32_16x16x32_bf16(bv3, pb, o[3], 0, 0, 0);
        if (kt < ktmax) {
          int kb = (kt + 1) * 32;
          bv0 = *(const short8*)(&vt_lds[fr * VTP + kb + fg * 8]);
          bv1 = *(const short8*)(&vt_lds[(16 + fr) * VTP + kb + fg * 8]);
          bv2 = *(const short8*)(&vt_lds[(32 + fr) * VTP + kb + fg * 8]);
          bv3 = *(const short8*)(&vt_lds[(48 + fr) * VTP + kb + fg * 8]);
        }
      }
      float inv = 1.f / l;
#pragma unroll
      for (int nt = 0; nt < 4; nt++) {
        float4_ ov = o[nt] * inv;
        *(float4_*)(&out[((size_t)b * Tt + qt * 16 + fr) * Hh + nt * 16 + fg * 4]) = ov;
      }
    };
    run_tile(wid);        // balanced causal split: 9 kt-steps per wave
    run_tile(15 - wid);

    if (bi == 0) __syncthreads();   // C(b0) LDS reads done before A(b1) staging
  }
}

extern "C" void kernel_launch(void* const* d_in, const int* in_sizes, int n_in,
                              void* d_out, int out_size, void* d_ws, size_t ws_size,
                              hipStream_t stream) {
  const float* x  = (const float*)d_in[0];
  const float* wq = (const float*)d_in[1];
  const float* wk = (const float*)d_in[2];
  const float* wv = (const float*)d_in[3];
  unsigned short* wt = (unsigned short*)d_ws;   // 192*384 bf16
  float* out = (float*)d_out;

  hipLaunchKernelGGL(wtrans_kernel, dim3(24),  dim3(256), 0, stream, wq, wk, wv, wt);
  hipLaunchKernelGGL(fused_kernel,  dim3(256), dim3(512), 0, stream, x, wt, out);
}

// Round 12
// 63.362 us; speedup vs baseline: 2.3929x; 2.3929x over previous
//
#include <hip/hip_runtime.h>
#include <hip/hip_bf16.h>
#include <math.h>

#define Bb 512
#define Tt 256
#define Cc 384
#define Hh 64

#define KP   72    // k_lds stride (shorts)
#define WPAD 72    // W buffer stride (shorts)
#define VTP  264   // V^T stride (shorts)
#define QBP  72    // q_lds stride (shorts)
#define PST  40    // P tile stride (shorts)
#define WCH  12288 // chunk-major W: 192*64 shorts per k-chunk

// LDS layout (shorts). Phase B/C regions; phase-A W double-buffer aliases the
// front (k_lds+vt region, temporally disjoint).
#define OFF_K  0
#define OFF_VT (256 * KP)                  // 18432
#define OFF_Q  (OFF_VT + 64 * VTP)         // 35328
#define OFF_P  (OFF_Q + 256 * QBP)         // 53760
#define LDST   (OFF_P + 8 * 16 * PST)      // 58880 shorts = 117,760 B
#define OFF_W0 0
#define OFF_W1 (192 * WPAD)                // 13824 (W1 ends 27648 < 35328)

typedef __attribute__((ext_vector_type(8))) short short8;
typedef __attribute__((ext_vector_type(4))) short short4_;
typedef __attribute__((ext_vector_type(4))) float float4_;

static __device__ __forceinline__ unsigned short f2bf(float f) {
  __hip_bfloat16 h = __float2bfloat16(f);
  return *reinterpret_cast<unsigned short*>(&h);
}

// ---------------- kernel 0: pack W chunk-major bf16: wt[ks][192][64] ----------------
__global__ __launch_bounds__(256) void wtrans_kernel(
    const float* __restrict__ wq, const float* __restrict__ wk,
    const float* __restrict__ wv, unsigned short* __restrict__ wt) {
  __shared__ float tl[384 * 8];
  const int blk = blockIdx.x;
  const int wsel = blk >> 3, n0 = (blk & 7) * 8;
  const float* w = (wsel == 0) ? wq : (wsel == 1) ? wk : wv;
  const int t = threadIdx.x;
#pragma unroll
  for (int i = 0; i < 3; i++) {
    int id = i * 256 + t;
    int row = id >> 1, sg = id & 1;
    float4_ v = *(const float4_*)(w + row * Hh + n0 + sg * 4);
    *(float4_*)(&tl[row * 8 + sg * 4]) = v;
  }
  __syncthreads();
#pragma unroll
  for (int i = 0; i < 12; i++) {
    int id = i * 256 + t;
    int n = id / 384, k = id % 384;
    int row = wsel * 64 + n0 + n;
    wt[(size_t)(k >> 6) * WCH + row * 64 + (k & 63)] = f2bf(tl[k * 8 + n]);
  }
}

// ---------------- fused kernel: per-batch QKV proj + causal flash attn ----------------
// Phase A (rebuilt): 8x1 wave grid — wave w owns rows [32w,32w+32) x all 192
// cols. x fragments go GLOBAL->REG directly (32 prefetch regs; R7's spill was
// the 64-reg 4x2 grid). W double-buffered in LDS, ONE lgkm barrier per chunk.
// Phases B/C: R8-verified swapped-operand flash attention.
// 512-thread blocks cap at 128 arch VGPRs in practice (R3/R7/R11 evidence);
// acc (96) lives in AGPRs; phase-A VGPR working set ~120.
__global__ __launch_bounds__(512, 1) void fused_kernel(
    const float* __restrict__ x, const unsigned short* __restrict__ wt,
    float* __restrict__ out) {
  __shared__ unsigned short lds[LDST];
  unsigned short* k_lds  = lds + OFF_K;
  unsigned short* vt_lds = lds + OFF_VT;
  unsigned short* q_lds  = lds + OFF_Q;

  const int t = threadIdx.x;
  const int wid = t >> 6, lane = t & 63;
  const int fr = lane & 15, fg = lane >> 4;
  const int b = blockIdx.x;
  const float* xb = x + (size_t)b * Tt * Cc;
  const float* xw = xb + (size_t)(wid * 32 + fr) * Cc + fg * 8;

  // ================= phase A: QKV = x[b] @ W  (M=256, N=192, K=384) =================
  float4_ acc[2][12];
#pragma unroll
  for (int i = 0; i < 2; i++)
#pragma unroll
    for (int j = 0; j < 12; j++) acc[i][j] = (float4_)0.f;

  // x fragments for chunk 0: rows wid*32+mi*16+fr, cols kk*32+fg*8.. (8 f32)
  float4_ nx[2][2][2];
#pragma unroll
  for (int mi = 0; mi < 2; mi++)
#pragma unroll
    for (int kk = 0; kk < 2; kk++)
#pragma unroll
      for (int h = 0; h < 2; h++)
        nx[mi][kk][h] = *(const float4_*)(xw + mi * 16 * Cc + kk * 32 + h * 4);

  // W chunk 0 -> regs
  short8 wv[3];
#pragma unroll
  for (int i = 0; i < 3; i++) {
    int id = t + i * 512;
    wv[i] = *(const short8*)(wt + (id >> 3) * 64 + (id & 7) * 8);
  }

#pragma unroll
  for (int ks = 0; ks < 6; ks++) {
    unsigned short* wb = lds + ((ks & 1) ? OFF_W1 : OFF_W0);
    // store W chunk ks (vmcnt wait for wv lands here)
#pragma unroll
    for (int i = 0; i < 3; i++) {
      int id = t + i * 512;
      *(short8*)(&wb[(id >> 3) * WPAD + (id & 7) * 8]) = wv[i];
    }
    // convert this chunk's x to bf16 A-frags (vmcnt waits land here)
    short8 af[2][2];
#pragma unroll
    for (int mi = 0; mi < 2; mi++)
#pragma unroll
      for (int kk = 0; kk < 2; kk++)
#pragma unroll
        for (int h = 0; h < 2; h++)
#pragma unroll
          for (int j = 0; j < 4; j++)
            af[mi][kk][h * 4 + j] = (short)f2bf(nx[mi][kk][h][j]);
    // issue chunk ks+1 loads (x frags + W); in flight across barrier + MFMAs
    if (ks < 5) {
#pragma unroll
      for (int mi = 0; mi < 2; mi++)
#pragma unroll
        for (int kk = 0; kk < 2; kk++)
#pragma unroll
          for (int h = 0; h < 2; h++)
            nx[mi][kk][h] = *(const float4_*)(xw + mi * 16 * Cc + (ks + 1) * 64 + kk * 32 + h * 4);
#pragma unroll
      for (int i = 0; i < 3; i++) {
        int id = t + i * 512;
        wv[i] = *(const short8*)(wt + (size_t)(ks + 1) * WCH + (id >> 3) * 64 + (id & 7) * 8);
      }
    }
    // ONE barrier per chunk: lgkm drained (W stores visible + prev MFMA ds_reads
    // done); vm loads stay in flight. Buffer ks+2 reuse is fenced by barrier ks+1.
    asm volatile("s_waitcnt lgkmcnt(0)" ::: "memory");
    __builtin_amdgcn_s_barrier();
    __builtin_amdgcn_sched_barrier(0);
#pragma unroll
    for (int kk = 0; kk < 2; kk++) {
#pragma unroll
      for (int ni = 0; ni < 12; ni++) {
        short8 bf = *(const short8*)(&wb[(ni * 16 + fr) * WPAD + kk * 32 + fg * 8]);
        acc[0][ni] = __builtin_amdgcn_mfma_f32_16x16x32_bf16(af[0][kk], bf, acc[0][ni], 0, 0, 0);
        acc[1][ni] = __builtin_amdgcn_mfma_f32_16x16x32_bf16(af[1][kk], bf, acc[1][ni], 0, 0, 0);
      }
    }
  }
  __syncthreads();   // end phase A: all W-buffer reads done before aliased scatter

  // ================= phase B: scatter Q/K/V into attention layouts =================
  // acc D-layout: row = wid*32 + mi*16 + fg*4 + r, col = ni*16 + fr
#pragma unroll
  for (int mi = 0; mi < 2; mi++) {
    int row0 = wid * 32 + mi * 16 + fg * 4;
#pragma unroll
    for (int ni = 0; ni < 12; ni++) {
      int col = ni * 16 + fr;
      if (ni >= 8) {                      // V cols 128..191 -> V^T [h][seq]
        short4_ pk;
#pragma unroll
        for (int r = 0; r < 4; r++) pk[r] = (short)f2bf(acc[mi][ni][r]);
        *(short4_*)(&vt_lds[(col - 128) * VTP + row0]) = pk;
      } else if (ni < 4) {                // Q cols 0..63 -> [seq][h]
#pragma unroll
        for (int r = 0; r < 4; r++)
          q_lds[(row0 + r) * QBP + col] = f2bf(acc[mi][ni][r]);
      } else {                            // K cols 64..127 -> [seq][h]
#pragma unroll
        for (int r = 0; r < 4; r++)
          k_lds[(row0 + r) * KP + (col - 64)] = f2bf(acc[mi][ni][r]);
      }
    }
  }
  __syncthreads();

  // ================= phase C: causal flash attn, swapped-operand layout =================
  unsigned short* pw = lds + OFF_P + wid * 16 * PST;   // wave-private [16 q][32 k]
  const float SC  = 0.05103103630798288f;              // 384^-0.5
  const float L2E = 1.4426950408889634f;

  auto run_tile = [&](int qt) {
    short8 aq0 = *(const short8*)(&q_lds[(qt * 16 + fr) * QBP + fg * 8]);
    short8 aq1 = *(const short8*)(&q_lds[(qt * 16 + fr) * QBP + 32 + fg * 8]);
    float4_ o[4] = {(float4_)0.f, (float4_)0.f, (float4_)0.f, (float4_)0.f};
    float m = -3.0e38f, l = 0.f;
    const int qg = qt * 16 + fr;
    const int ktmax = qt >> 1;
    short8 kf0 = *(const short8*)(&k_lds[fr * KP + fg * 8]);
    short8 kf1 = *(const short8*)(&k_lds[(16 + fr) * KP + fg * 8]);
    short8 kf2 = *(const short8*)(&k_lds[fr * KP + 32 + fg * 8]);
    short8 kf3 = *(const short8*)(&k_lds[(16 + fr) * KP + 32 + fg * 8]);
    short8 bv0 = *(const short8*)(&vt_lds[fr * VTP + fg * 8]);
    short8 bv1 = *(const short8*)(&vt_lds[(16 + fr) * VTP + fg * 8]);
    short8 bv2 = *(const short8*)(&vt_lds[(32 + fr) * VTP + fg * 8]);
    short8 bv3 = *(const short8*)(&vt_lds[(48 + fr) * VTP + fg * 8]);
    for (int kt = 0; kt <= ktmax; kt++) {
      float4_ s0 = (float4_)0.f, s1 = (float4_)0.f;
      s0 = __builtin_amdgcn_mfma_f32_16x16x32_bf16(kf0, aq0, s0, 0, 0, 0);
      s1 = __builtin_amdgcn_mfma_f32_16x16x32_bf16(kf1, aq0, s1, 0, 0, 0);
      s0 = __builtin_amdgcn_mfma_f32_16x16x32_bf16(kf2, aq1, s0, 0, 0, 0);
      s1 = __builtin_amdgcn_mfma_f32_16x16x32_bf16(kf3, aq1, s1, 0, 0, 0);
      if (kt < ktmax) {
        int kb = (kt + 1) * 32;
        kf0 = *(const short8*)(&k_lds[(kb + fr) * KP + fg * 8]);
        kf1 = *(const short8*)(&k_lds[(kb + 16 + fr) * KP + fg * 8]);
        kf2 = *(const short8*)(&k_lds[(kb + fr) * KP + 32 + fg * 8]);
        kf3 = *(const short8*)(&k_lds[(kb + 16 + fr) * KP + 32 + fg * 8]);
      }
      bool edge = (kt == ktmax);
      float vs[8];
#pragma unroll
      for (int r = 0; r < 4; r++) {
        int kg0 = kt * 32 + fg * 4 + r;
        float a0 = s0[r] * SC, a1 = s1[r] * SC;
        if (edge && kg0 > qg)      a0 = -3.0e38f;
        if (edge && kg0 + 16 > qg) a1 = -3.0e38f;
        vs[r] = a0; vs[4 + r] = a1;
      }
      float mx = fmaxf(fmaxf(fmaxf(vs[0], vs[1]), fmaxf(vs[2], vs[3])),
                       fmaxf(fmaxf(vs[4], vs[5]), fmaxf(vs[6], vs[7])));
      mx = fmaxf(mx, __shfl_xor(mx, 16));
      mx = fmaxf(mx, __shfl_xor(mx, 32));
      if (!__all(mx - m <= 8.0f)) {   // defer-rescale (T13, THR=8)
        float mn = fmaxf(m, mx);
        float scal = exp2f((m - mn) * L2E);
        l *= scal;
#pragma unroll
        for (int nt = 0; nt < 4; nt++) o[nt] *= scal;
        m = mn;
      }
      float p[8]; float ps = 0.f;
#pragma unroll
      for (int j = 0; j < 8; j++) { p[j] = exp2f((vs[j] - m) * L2E); ps += p[j]; }
      ps += __shfl_xor(ps, 16);
      ps += __shfl_xor(ps, 32);
      l += ps;

      short4_ pk0, pk1;
#pragma unroll
      for (int r = 0; r < 4; r++) { pk0[r] = (short)f2bf(p[r]); pk1[r] = (short)f2bf(p[4 + r]); }
      *(short4_*)(&pw[fr * PST + fg * 4]) = pk0;
      *(short4_*)(&pw[fr * PST + 16 + fg * 4]) = pk1;
      asm volatile("s_waitcnt lgkmcnt(0)" ::: "memory");
      __builtin_amdgcn_sched_barrier(0);
      short8 pb = *(const short8*)(&pw[fr * PST + fg * 8]);
      o[0] = __builtin_amdgcn_mfma_f32_16x16x32_bf16(bv0, pb, o[0], 0, 0, 0);
      o[1] = __builtin_amdgcn_mfma_f32_16x16x32_bf16(bv1, pb, o[1], 0, 0, 0);
      o[2] = __builtin_amdgcn_mfma_f32_16x16x32_bf16(bv2, pb, o[2], 0, 0, 0);
      o[3] = __builtin_amdgcn_mfma_f32_16x16x32_bf16(bv3, pb, o[3], 0, 0, 0);
      if (kt < ktmax) {
        int kb = (kt + 1) * 32;
        bv0 = *(const short8*)(&vt_lds[fr * VTP + kb + fg * 8]);
        bv1 = *(const short8*)(&vt_lds[(16 + fr) * VTP + kb + fg * 8]);
        bv2 = *(const short8*)(&vt_lds[(32 + fr) * VTP + kb + fg * 8]);
        bv3 = *(const short8*)(&vt_lds[(48 + fr) * VTP + kb + fg * 8]);
      }
    }
    float inv = 1.f / l;
#pragma unroll
    for (int nt = 0; nt < 4; nt++) {
      float4_ ov = o[nt] * inv;
      *(float4_*)(&out[((size_t)b * Tt + qt * 16 + fr) * Hh + nt * 16 + fg * 4]) = ov;
    }
  };
  run_tile(wid);        // balanced causal split: 9 kt-steps per wave
  run_tile(15 - wid);
}

extern "C" void kernel_launch(void* const* d_in, const int* in_sizes, int n_in,
                              void* d_out, int out_size, void* d_ws, size_t ws_size,
                              hipStream_t stream) {
  const float* x  = (const float*)d_in[0];
  const float* wq = (const float*)d_in[1];
  const float* wk = (const float*)d_in[2];
  const float* wv = (const float*)d_in[3];
  unsigned short* wt = (unsigned short*)d_ws;   // 6 chunks x 192*64 bf16
  float* out = (float*)d_out;

  hipLaunchKernelGGL(wtrans_kernel, dim3(24), dim3(256), 0, stream, wq, wk, wv, wt);
  hipLaunchKernelGGL(fused_kernel,  dim3(Bb), dim3(512), 0, stream, x, wt, out);
}